// Round 7
// baseline (177.193 us; speedup 1.0000x reference)
//
#include <hip/hip_runtime.h>
#include <math.h>

#define S_SIMS 4096
#define T_LEN  500
#define T_HALF 250
#define D_DIM  6
#define A_DIM  3
#define H_DIM  64
#define ALPHA_C 0.1f
#define NT 4     // t-points per lane: ceil(250/64)
#define WPK 20   // packed floats per hidden unit (80 B, 16B-aligned stride)

// ---------------------------------------------------------------------------
// Pack kernel: all 8 weight tensors -> contiguous [H][20] layout in d_ws.
// 0..5 pW1[j][:] | 6 pb1[j] | 7..9 pW2[:][j] | 10 bb1[j] | 11 bW2[j]
// 12..17 bW1[j][:] | 18..19 pad
// ---------------------------------------------------------------------------
__global__ __launch_bounds__(64) void mepg_pack(
    const float* __restrict__ pW1, const float* __restrict__ pb1,
    const float* __restrict__ pW2, const float* __restrict__ pb2,
    const float* __restrict__ bW1, const float* __restrict__ bb1,
    const float* __restrict__ bW2, const float* __restrict__ bb2,
    float* __restrict__ wq)
{
    const int j = threadIdx.x;
    float* w = &wq[j * WPK];
#pragma unroll
    for (int d = 0; d < D_DIM; ++d) w[d] = pW1[j * D_DIM + d];
    w[6]  = pb1[j];
    w[7]  = pW2[0 * H_DIM + j];
    w[8]  = pW2[1 * H_DIM + j];
    w[9]  = pW2[2 * H_DIM + j];
    w[10] = bb1[j];
    w[11] = bW2[j];
#pragma unroll
    for (int d = 0; d < D_DIM; ++d) w[12 + d] = bW1[j * D_DIM + d];
    w[18] = 0.f; w[19] = 0.f;
}

// ---------------------------------------------------------------------------
// Main kernel: one wave per HALF-simulation (250 t). No LDS. Weights are
// wave-uniform reads through a read-only restrict pointer -> SMEM (s_load),
// issued on the scalar pipe; every VALU slot is an fma/max of the MLP math.
// ---------------------------------------------------------------------------
__global__ __launch_bounds__(256, 6) void mepg_main(
    const float* __restrict__ state,   // [S, D, T]
    const float* __restrict__ action,  // [S, A, T]
    const float* __restrict__ reward,  // [S, T]
    const float* __restrict__ wq,      // [H][WPK] packed weights
    const float* __restrict__ pb2,     // [A]
    const float* __restrict__ bb2,     // [1]
    const float* __restrict__ sd,      // [A, A]
    float* __restrict__ ASp,           // [2, S] partial AS
    float* __restrict__ SLp)           // [2, S] partial SL
{
    // ---- sd^{-1} (3x3 symmetric) + log-det constant (uniform -> SALU/SMEM) --
    const float s00 = sd[0], s01 = sd[1], s02 = sd[2];
    const float s11 = sd[4], s12 = sd[5], s22 = sd[8];
    const float det = s00 * (s11 * s22 - s12 * s12)
                    - s01 * (s01 * s22 - s12 * s02)
                    + s02 * (s01 * s12 - s11 * s02);
    const float idet = 1.0f / det;
    const float M00 = (s11 * s22 - s12 * s12) * idet;
    const float M01 = (s02 * s12 - s01 * s22) * idet;
    const float M02 = (s01 * s12 - s02 * s11) * idet;
    const float M11 = (s00 * s22 - s02 * s02) * idet;
    const float M12 = (s01 * s02 - s00 * s12) * idet;
    const float M22 = (s00 * s11 - s01 * s01) * idet;
    const float c0 = -0.5f * logf(det) - 0.5f * (float)A_DIM * logf(6.2831853071795864769f);

    const float pb2_0 = pb2[0], pb2_1 = pb2[1], pb2_2 = pb2[2];
    const float bb2_0 = bb2[0];

    const int tid  = threadIdx.x;
    const int wave = tid >> 6;
    const int lane = tid & 63;
    const int wid  = blockIdx.x * 4 + wave;   // 0..8191
    const int s    = wid >> 1;
    const int half = wid & 1;
    const int tbase = half * T_HALF;

    const float* sbase = state  + (size_t)s * D_DIM * T_LEN + tbase;
    const float* abase = action + (size_t)s * A_DIM * T_LEN + tbase;
    const float* rbase = reward + (size_t)s * T_LEN + tbase;

    // ---- load this lane's NT state points into registers -------------------
    float x[D_DIM][NT];
#pragma unroll
    for (int k = 0; k < NT; ++k) {
        const int tl = lane + 64 * k;
        const bool v = (tl < T_HALF);
        const int tc = v ? tl : 0;
#pragma unroll
        for (int d = 0; d < D_DIM; ++d)
            x[d][k] = v ? sbase[d * T_LEN + tc] : 0.f;
    }

    float mu0[NT], mu1[NT], mu2[NT], bl[NT];
#pragma unroll
    for (int k = 0; k < NT; ++k) {
        mu0[k] = pb2_0; mu1[k] = pb2_1; mu2[k] = pb2_2; bl[k] = bb2_0;
    }

    // ---- hidden-unit loop: weights are uniform scalars (SGPRs) -------------
    for (int j = 0; j < H_DIM; ++j) {
        const float* w = wq + j * WPK;
        const float w0  = w[0],  w1  = w[1],  w2  = w[2],  w3  = w[3];
        const float w4  = w[4],  w5  = w[5],  w6  = w[6],  w7  = w[7];
        const float w8  = w[8],  w9  = w[9],  w10 = w[10], w11 = w[11];
        const float w12 = w[12], w13 = w[13], w14 = w[14], w15 = w[15];
        const float w16 = w[16], w17 = w[17];
#pragma unroll
        for (int k = 0; k < NT; ++k) {
            const float pre = fmaf(x[0][k], w0, fmaf(x[1][k], w1, fmaf(x[2][k], w2,
                              fmaf(x[3][k], w3, fmaf(x[4][k], w4, fmaf(x[5][k], w5, w6))))));
            const float h = fmaxf(pre, 0.f);
            mu0[k] = fmaf(h, w7, mu0[k]);
            mu1[k] = fmaf(h, w8, mu1[k]);
            mu2[k] = fmaf(h, w9, mu2[k]);
            const float preb = fmaf(x[0][k], w12, fmaf(x[1][k], w13, fmaf(x[2][k], w14,
                               fmaf(x[3][k], w15, fmaf(x[4][k], w16, fmaf(x[5][k], w17, w10))))));
            const float hb = fmaxf(preb, 0.f);
            bl[k] = fmaf(hb, w11, bl[k]);
        }
    }

    // ---- epilogue: residual, loglik, advantage -----------------------------
    float SL = 0.f;
    float AS = 0.f;
#pragma unroll
    for (int k = 0; k < NT; ++k) {
        const int tl = lane + 64 * k;
        if (tl < T_HALF) {
            const float a0 = abase[0 * T_LEN + tl];
            const float a1 = abase[1 * T_LEN + tl];
            const float a2 = abase[2 * T_LEN + tl];
            const float r  = rbase[tl];
            const float d0 = a0 - mu0[k];
            const float d1 = a1 - mu1[k];
            const float d2 = a2 - mu2[k];
            const float q  = M00 * d0 * d0 + M11 * d1 * d1 + M22 * d2 * d2
                           + 2.f * (M01 * d0 * d1 + M02 * d0 * d2 + M12 * d1 * d2);
            const float ll = -0.5f * q + c0;
            const float g  = __expf(r) - ALPHA_C * ll;
            SL += ll;
            AS += (float)(tbase + tl + 1) * g - bl[k];
        }
    }

#pragma unroll
    for (int o = 32; o > 0; o >>= 1) {
        SL += __shfl_xor(SL, o, 64);
        AS += __shfl_xor(AS, o, 64);
    }
    if (lane == 0) {
        ASp[half * S_SIMS + s] = AS;
        SLp[half * S_SIMS + s] = SL;
    }
}

// ---------------------------------------------------------------------------
// out = sum_s (AS0[s]+AS1[s])*(SL0[s]+SL1[s]) / (T*S), f64 accumulate.
// ---------------------------------------------------------------------------
__global__ __launch_bounds__(1024) void mepg_reduce(
    const float* __restrict__ ASp, const float* __restrict__ SLp,
    float* __restrict__ out)
{
    __shared__ double sh[16];
    double acc = 0.0;
    for (int i = threadIdx.x; i < S_SIMS; i += 1024) {
        const double a = (double)ASp[i] + (double)ASp[S_SIMS + i];
        const double l = (double)SLp[i] + (double)SLp[S_SIMS + i];
        acc += a * l;
    }
#pragma unroll
    for (int o = 32; o > 0; o >>= 1)
        acc += __shfl_xor(acc, o, 64);
    const int w = threadIdx.x >> 6, l = threadIdx.x & 63;
    if (l == 0) sh[w] = acc;
    __syncthreads();
    if (threadIdx.x < 16) {
        double a = sh[threadIdx.x];
#pragma unroll
        for (int o = 8; o > 0; o >>= 1)
            a += __shfl_xor(a, o, 16);
        if (threadIdx.x == 0)
            out[0] = (float)(a / ((double)T_LEN * (double)S_SIMS));
    }
}

extern "C" void kernel_launch(void* const* d_in, const int* in_sizes, int n_in,
                              void* d_out, int out_size, void* d_ws, size_t ws_size,
                              hipStream_t stream) {
    const float* state  = (const float*)d_in[0];
    const float* action = (const float*)d_in[1];
    const float* reward = (const float*)d_in[2];
    const float* pW1    = (const float*)d_in[3];
    const float* pb1    = (const float*)d_in[4];
    const float* pW2    = (const float*)d_in[5];
    const float* pb2    = (const float*)d_in[6];
    const float* bW1    = (const float*)d_in[7];
    const float* bb1    = (const float*)d_in[8];
    const float* bW2    = (const float*)d_in[9];
    const float* bb2    = (const float*)d_in[10];
    const float* sd     = (const float*)d_in[11];

    float* ASp = (float*)d_ws;                 // [2*S]
    float* SLp = ASp + 2 * S_SIMS;             // [2*S]
    float* wq  = SLp + 2 * S_SIMS;             // [H*WPK]

    mepg_pack<<<1, 64, 0, stream>>>(pW1, pb1, pW2, pb2, bW1, bb1, bW2, bb2, wq);

    dim3 block(256);
    dim3 grid(2 * S_SIMS / 4);                 // 8192 waves, 4 per block
    mepg_main<<<grid, block, 0, stream>>>(state, action, reward, wq,
                                          pb2, bb2, sd, ASp, SLp);
    mepg_reduce<<<1, 1024, 0, stream>>>(ASp, SLp, (float*)d_out);
}

// Round 8
// 164.983 us; speedup vs baseline: 1.0740x; 1.0740x over previous
//
#include <hip/hip_runtime.h>
#include <math.h>

#define S_SIMS 4096
#define T_LEN  500
#define T_HALF 250
#define D_DIM  6
#define A_DIM  3
#define H_DIM  64
#define ALPHA_C 0.1f
#define NT 4     // t-points per lane: ceil(250/64)
#define WPK 20   // packed floats per hidden unit (80 B)

typedef float v2f __attribute__((ext_vector_type(2)));
static __device__ __forceinline__ v2f v2splat(float s) { v2f r; r.x = s; r.y = s; return r; }
static __device__ __forceinline__ v2f v2fma(v2f a, float b, v2f c) {
    return __builtin_elementwise_fma(a, v2splat(b), c);
}

// ---------------------------------------------------------------------------
// Pack kernel: all 8 weight tensors -> contiguous [H][20] layout in d_ws.
// 0..5 pW1[j][:] | 6 pb1[j] | 7..9 pW2[:][j] | 10 bb1[j] | 11 bW2[j]
// 12..17 bW1[j][:] | 18..19 pad
// ---------------------------------------------------------------------------
__global__ __launch_bounds__(64) void mepg_pack(
    const float* __restrict__ pW1, const float* __restrict__ pb1,
    const float* __restrict__ pW2, const float* __restrict__ pb2,
    const float* __restrict__ bW1, const float* __restrict__ bb1,
    const float* __restrict__ bW2, const float* __restrict__ bb2,
    float* __restrict__ wq)
{
    const int j = threadIdx.x;
    float* w = &wq[j * WPK];
#pragma unroll
    for (int d = 0; d < D_DIM; ++d) w[d] = pW1[j * D_DIM + d];
    w[6]  = pb1[j];
    w[7]  = pW2[0 * H_DIM + j];
    w[8]  = pW2[1 * H_DIM + j];
    w[9]  = pW2[2 * H_DIM + j];
    w[10] = bb1[j];
    w[11] = bW2[j];
#pragma unroll
    for (int d = 0; d < D_DIM; ++d) w[12 + d] = bW1[j * D_DIM + d];
    w[18] = 0.f; w[19] = 0.f;
}

// ---------------------------------------------------------------------------
// Main kernel: one wave per HALF-simulation (250 t). No LDS; weights are
// wave-uniform -> SMEM/SGPR (verified round 6: SGPR=96, 44 us). The j-loop
// math runs on float2 ext-vectors (pairs of t-points) so clang emits
// v_pk_fma_f32 (2x f32 throughput, VOP3P) on gfx950.
// ---------------------------------------------------------------------------
__global__ __launch_bounds__(256, 4) void mepg_main(
    const float* __restrict__ state,   // [S, D, T]
    const float* __restrict__ action,  // [S, A, T]
    const float* __restrict__ reward,  // [S, T]
    const float* __restrict__ wq,      // [H][WPK] packed weights
    const float* __restrict__ pb2,     // [A]
    const float* __restrict__ bb2,     // [1]
    const float* __restrict__ sd,      // [A, A]
    float* __restrict__ ASp,           // [2, S] partial AS
    float* __restrict__ SLp)           // [2, S] partial SL
{
    // ---- sd^{-1} (3x3 symmetric) + log-det constant (uniform) --------------
    const float s00 = sd[0], s01 = sd[1], s02 = sd[2];
    const float s11 = sd[4], s12 = sd[5], s22 = sd[8];
    const float det = s00 * (s11 * s22 - s12 * s12)
                    - s01 * (s01 * s22 - s12 * s02)
                    + s02 * (s01 * s12 - s11 * s02);
    const float idet = 1.0f / det;
    const float M00 = (s11 * s22 - s12 * s12) * idet;
    const float M01 = (s02 * s12 - s01 * s22) * idet;
    const float M02 = (s01 * s12 - s02 * s11) * idet;
    const float M11 = (s00 * s22 - s02 * s02) * idet;
    const float M12 = (s01 * s02 - s00 * s12) * idet;
    const float M22 = (s00 * s11 - s01 * s01) * idet;
    const float c0 = -0.5f * logf(det) - 0.5f * (float)A_DIM * logf(6.2831853071795864769f);

    const float pb2_0 = pb2[0], pb2_1 = pb2[1], pb2_2 = pb2[2];
    const float bb2_0 = bb2[0];

    const int tid  = threadIdx.x;
    const int wave = tid >> 6;
    const int lane = tid & 63;
    const int wid  = blockIdx.x * 4 + wave;   // 0..8191
    const int s    = wid >> 1;
    const int half = wid & 1;
    const int tbase = half * T_HALF;

    const float* sbase = state  + (size_t)s * D_DIM * T_LEN + tbase;
    const float* abase = action + (size_t)s * A_DIM * T_LEN + tbase;
    const float* rbase = reward + (size_t)s * T_LEN + tbase;

    // ---- load this lane's NT=4 state points as 2 float2 pairs --------------
    // pair p holds t-points k=2p (x) and k=2p+1 (y); t = lane + 64*k
    v2f x[D_DIM][2];
#pragma unroll
    for (int p = 0; p < 2; ++p) {
#pragma unroll
        for (int d = 0; d < D_DIM; ++d) {
            const int t0 = lane + 64 * (2 * p);
            const int t1 = lane + 64 * (2 * p + 1);
            const float e0 = (t0 < T_HALF) ? sbase[d * T_LEN + t0] : 0.f;
            const float e1 = (t1 < T_HALF) ? sbase[d * T_LEN + t1] : 0.f;
            v2f v; v.x = e0; v.y = e1;
            x[d][p] = v;
        }
    }

    v2f mu0[2], mu1[2], mu2[2], bl[2];
#pragma unroll
    for (int p = 0; p < 2; ++p) {
        mu0[p] = v2splat(pb2_0); mu1[p] = v2splat(pb2_1);
        mu2[p] = v2splat(pb2_2); bl[p]  = v2splat(bb2_0);
    }

    // ---- hidden-unit loop: scalar (SGPR) weights x packed-f32 math ---------
#pragma unroll 2
    for (int j = 0; j < H_DIM; ++j) {
        const float* w = wq + j * WPK;
        const float w0  = w[0],  w1  = w[1],  w2  = w[2],  w3  = w[3];
        const float w4  = w[4],  w5  = w[5],  w6  = w[6],  w7  = w[7];
        const float w8  = w[8],  w9  = w[9],  w10 = w[10], w11 = w[11];
        const float w12 = w[12], w13 = w[13], w14 = w[14], w15 = w[15];
        const float w16 = w[16], w17 = w[17];
#pragma unroll
        for (int p = 0; p < 2; ++p) {
            v2f pre = v2fma(x[0][p], w0, v2fma(x[1][p], w1, v2fma(x[2][p], w2,
                      v2fma(x[3][p], w3, v2fma(x[4][p], w4, v2fma(x[5][p], w5, v2splat(w6)))))));
            const v2f h = __builtin_elementwise_max(pre, v2splat(0.f));
            mu0[p] = v2fma(h, w7, mu0[p]);
            mu1[p] = v2fma(h, w8, mu1[p]);
            mu2[p] = v2fma(h, w9, mu2[p]);
            v2f preb = v2fma(x[0][p], w12, v2fma(x[1][p], w13, v2fma(x[2][p], w14,
                       v2fma(x[3][p], w15, v2fma(x[4][p], w16, v2fma(x[5][p], w17, v2splat(w10)))))));
            const v2f hb = __builtin_elementwise_max(preb, v2splat(0.f));
            bl[p] = v2fma(hb, w11, bl[p]);
        }
    }

    // ---- epilogue: residual, loglik, advantage -----------------------------
    float SL = 0.f;
    float AS = 0.f;
#pragma unroll
    for (int k = 0; k < NT; ++k) {
        const int tl = lane + 64 * k;
        if (tl < T_HALF) {
            const int p = k >> 1;
            const int e = k & 1;
            const float m0 = e ? mu0[p].y : mu0[p].x;
            const float m1 = e ? mu1[p].y : mu1[p].x;
            const float m2 = e ? mu2[p].y : mu2[p].x;
            const float bv = e ? bl[p].y  : bl[p].x;
            const float a0 = abase[0 * T_LEN + tl];
            const float a1 = abase[1 * T_LEN + tl];
            const float a2 = abase[2 * T_LEN + tl];
            const float r  = rbase[tl];
            const float d0 = a0 - m0;
            const float d1 = a1 - m1;
            const float d2 = a2 - m2;
            const float q  = M00 * d0 * d0 + M11 * d1 * d1 + M22 * d2 * d2
                           + 2.f * (M01 * d0 * d1 + M02 * d0 * d2 + M12 * d1 * d2);
            const float ll = -0.5f * q + c0;
            const float g  = __expf(r) - ALPHA_C * ll;
            SL += ll;
            AS += (float)(tbase + tl + 1) * g - bv;
        }
    }

#pragma unroll
    for (int o = 32; o > 0; o >>= 1) {
        SL += __shfl_xor(SL, o, 64);
        AS += __shfl_xor(AS, o, 64);
    }
    if (lane == 0) {
        ASp[half * S_SIMS + s] = AS;
        SLp[half * S_SIMS + s] = SL;
    }
}

// ---------------------------------------------------------------------------
// out = sum_s (AS0[s]+AS1[s])*(SL0[s]+SL1[s]) / (T*S), f64 accumulate.
// ---------------------------------------------------------------------------
__global__ __launch_bounds__(1024) void mepg_reduce(
    const float* __restrict__ ASp, const float* __restrict__ SLp,
    float* __restrict__ out)
{
    __shared__ double sh[16];
    double acc = 0.0;
    for (int i = threadIdx.x; i < S_SIMS; i += 1024) {
        const double a = (double)ASp[i] + (double)ASp[S_SIMS + i];
        const double l = (double)SLp[i] + (double)SLp[S_SIMS + i];
        acc += a * l;
    }
#pragma unroll
    for (int o = 32; o > 0; o >>= 1)
        acc += __shfl_xor(acc, o, 64);
    const int w = threadIdx.x >> 6, l = threadIdx.x & 63;
    if (l == 0) sh[w] = acc;
    __syncthreads();
    if (threadIdx.x < 16) {
        double a = sh[threadIdx.x];
#pragma unroll
        for (int o = 8; o > 0; o >>= 1)
            a += __shfl_xor(a, o, 16);
        if (threadIdx.x == 0)
            out[0] = (float)(a / ((double)T_LEN * (double)S_SIMS));
    }
}

extern "C" void kernel_launch(void* const* d_in, const int* in_sizes, int n_in,
                              void* d_out, int out_size, void* d_ws, size_t ws_size,
                              hipStream_t stream) {
    const float* state  = (const float*)d_in[0];
    const float* action = (const float*)d_in[1];
    const float* reward = (const float*)d_in[2];
    const float* pW1    = (const float*)d_in[3];
    const float* pb1    = (const float*)d_in[4];
    const float* pW2    = (const float*)d_in[5];
    const float* pb2    = (const float*)d_in[6];
    const float* bW1    = (const float*)d_in[7];
    const float* bb1    = (const float*)d_in[8];
    const float* bW2    = (const float*)d_in[9];
    const float* bb2    = (const float*)d_in[10];
    const float* sd     = (const float*)d_in[11];

    float* ASp = (float*)d_ws;                 // [2*S]
    float* SLp = ASp + 2 * S_SIMS;             // [2*S]
    float* wq  = SLp + 2 * S_SIMS;             // [H*WPK]

    mepg_pack<<<1, 64, 0, stream>>>(pW1, pb1, pW2, pb2, bW1, bb1, bW2, bb2, wq);

    dim3 block(256);
    dim3 grid(2 * S_SIMS / 4);                 // 8192 waves, 4 per block
    mepg_main<<<grid, block, 0, stream>>>(state, action, reward, wq,
                                          pb2, bb2, sd, ASp, SLp);
    mepg_reduce<<<1, 1024, 0, stream>>>(ASp, SLp, (float*)d_out);
}

// Round 9
// 160.675 us; speedup vs baseline: 1.1028x; 1.0268x over previous
//
#include <hip/hip_runtime.h>
#include <math.h>

#define S_SIMS 4096
#define T_LEN  500
#define TQ     125   // t-points per wave (quarter simulation)
#define NQ     4     // quarters per simulation
#define D_DIM  6
#define A_DIM  3
#define H_DIM  64
#define ALPHA_C 0.1f
#define WPK 20       // packed floats per hidden unit (80 B)

typedef float v2f __attribute__((ext_vector_type(2)));
static __device__ __forceinline__ v2f v2splat(float s) { v2f r; r.x = s; r.y = s; return r; }
static __device__ __forceinline__ v2f v2fma(v2f a, float b, v2f c) {
    return __builtin_elementwise_fma(a, v2splat(b), c);
}

// ---------------------------------------------------------------------------
// Pack kernel: all 8 weight tensors -> contiguous [H][20] layout in d_ws.
// 0..5 pW1[j][:] | 6 pb1[j] | 7..9 pW2[:][j] | 10 bb1[j] | 11 bW2[j]
// 12..17 bW1[j][:] | 18..19 pad
// ---------------------------------------------------------------------------
__global__ __launch_bounds__(64) void mepg_pack(
    const float* __restrict__ pW1, const float* __restrict__ pb1,
    const float* __restrict__ pW2, const float* __restrict__ pb2,
    const float* __restrict__ bW1, const float* __restrict__ bb1,
    const float* __restrict__ bW2, const float* __restrict__ bb2,
    float* __restrict__ wq)
{
    const int j = threadIdx.x;
    float* w = &wq[j * WPK];
#pragma unroll
    for (int d = 0; d < D_DIM; ++d) w[d] = pW1[j * D_DIM + d];
    w[6]  = pb1[j];
    w[7]  = pW2[0 * H_DIM + j];
    w[8]  = pW2[1 * H_DIM + j];
    w[9]  = pW2[2 * H_DIM + j];
    w[10] = bb1[j];
    w[11] = bW2[j];
#pragma unroll
    for (int d = 0; d < D_DIM; ++d) w[12 + d] = bW1[j * D_DIM + d];
    w[18] = 0.f; w[19] = 0.f;
}

// ---------------------------------------------------------------------------
// Main kernel: one wave per QUARTER-simulation (125 t-points, 2 per lane in
// one v2f). J-loop live set ~26 VGPRs -- below any allocator squeeze point,
// so no rematerialization. Weights wave-uniform -> SGPR via SMEM (verified
// round 6). Math on v2f so clang can emit v_pk_fma_f32 (2x f32 rate).
// ---------------------------------------------------------------------------
__global__ __launch_bounds__(256, 8) void mepg_main(
    const float* __restrict__ state,   // [S, D, T]
    const float* __restrict__ action,  // [S, A, T]
    const float* __restrict__ reward,  // [S, T]
    const float* __restrict__ wq,      // [H][WPK] packed weights
    const float* __restrict__ pb2,     // [A]
    const float* __restrict__ bb2,     // [1]
    const float* __restrict__ sd,      // [A, A]
    float* __restrict__ ASp,           // [NQ, S] partial AS
    float* __restrict__ SLp)           // [NQ, S] partial SL
{
    // ---- sd^{-1} (3x3 symmetric) + log-det constant (uniform) --------------
    const float s00 = sd[0], s01 = sd[1], s02 = sd[2];
    const float s11 = sd[4], s12 = sd[5], s22 = sd[8];
    const float det = s00 * (s11 * s22 - s12 * s12)
                    - s01 * (s01 * s22 - s12 * s02)
                    + s02 * (s01 * s12 - s11 * s02);
    const float idet = 1.0f / det;
    const float M00 = (s11 * s22 - s12 * s12) * idet;
    const float M01 = (s02 * s12 - s01 * s22) * idet;
    const float M02 = (s01 * s12 - s02 * s11) * idet;
    const float M11 = (s00 * s22 - s02 * s02) * idet;
    const float M12 = (s01 * s02 - s00 * s12) * idet;
    const float M22 = (s00 * s11 - s01 * s01) * idet;
    const float c0 = -0.5f * logf(det) - 0.5f * (float)A_DIM * logf(6.2831853071795864769f);

    const float pb2_0 = pb2[0], pb2_1 = pb2[1], pb2_2 = pb2[2];
    const float bb2_0 = bb2[0];

    const int tid  = threadIdx.x;
    const int wave = tid >> 6;
    const int lane = tid & 63;
    const int wid  = blockIdx.x * 4 + wave;   // 0..16383
    const int s    = wid >> 2;
    const int q    = wid & 3;
    const int tbase = q * TQ;

    const float* sbase = state  + (size_t)s * D_DIM * T_LEN + tbase;
    const float* abase = action + (size_t)s * A_DIM * T_LEN + tbase;
    const float* rbase = reward + (size_t)s * T_LEN + tbase;

    // ---- load this lane's 2 state points into one v2f per dim --------------
    // t0 = lane (always < 125), t1 = lane + 64 (valid iff lane < 61)
    const bool v1 = (lane + 64) < TQ;
    v2f x[D_DIM];
#pragma unroll
    for (int d = 0; d < D_DIM; ++d) {
        v2f v;
        v.x = sbase[d * T_LEN + lane];
        v.y = v1 ? sbase[d * T_LEN + lane + 64] : 0.f;
        x[d] = v;
    }

    v2f mu0 = v2splat(pb2_0), mu1 = v2splat(pb2_1), mu2 = v2splat(pb2_2);
    v2f bl  = v2splat(bb2_0);

    // ---- hidden-unit loop: SGPR weights x packed-f32 math ------------------
#pragma unroll 2
    for (int j = 0; j < H_DIM; ++j) {
        const float* w = wq + j * WPK;
        const float w0  = w[0],  w1  = w[1],  w2  = w[2],  w3  = w[3];
        const float w4  = w[4],  w5  = w[5],  w6  = w[6],  w7  = w[7];
        const float w8  = w[8],  w9  = w[9],  w10 = w[10], w11 = w[11];
        const float w12 = w[12], w13 = w[13], w14 = w[14], w15 = w[15];
        const float w16 = w[16], w17 = w[17];

        v2f pre = v2fma(x[0], w0, v2fma(x[1], w1, v2fma(x[2], w2,
                  v2fma(x[3], w3, v2fma(x[4], w4, v2fma(x[5], w5, v2splat(w6)))))));
        const v2f h = __builtin_elementwise_max(pre, v2splat(0.f));
        mu0 = v2fma(h, w7, mu0);
        mu1 = v2fma(h, w8, mu1);
        mu2 = v2fma(h, w9, mu2);
        v2f preb = v2fma(x[0], w12, v2fma(x[1], w13, v2fma(x[2], w14,
                   v2fma(x[3], w15, v2fma(x[4], w16, v2fma(x[5], w17, v2splat(w10)))))));
        const v2f hb = __builtin_elementwise_max(preb, v2splat(0.f));
        bl = v2fma(hb, w11, bl);
    }

    // ---- epilogue: residual, loglik, advantage -----------------------------
    float SL = 0.f;
    float AS = 0.f;
#pragma unroll
    for (int k = 0; k < 2; ++k) {
        const int tl = lane + 64 * k;
        if (k == 0 || v1) {
            const float m0 = k ? mu0.y : mu0.x;
            const float m1 = k ? mu1.y : mu1.x;
            const float m2 = k ? mu2.y : mu2.x;
            const float bv = k ? bl.y  : bl.x;
            const float a0 = abase[0 * T_LEN + tl];
            const float a1 = abase[1 * T_LEN + tl];
            const float a2 = abase[2 * T_LEN + tl];
            const float r  = rbase[tl];
            const float d0 = a0 - m0;
            const float d1 = a1 - m1;
            const float d2 = a2 - m2;
            const float qd = M00 * d0 * d0 + M11 * d1 * d1 + M22 * d2 * d2
                           + 2.f * (M01 * d0 * d1 + M02 * d0 * d2 + M12 * d1 * d2);
            const float ll = -0.5f * qd + c0;
            const float g  = __expf(r) - ALPHA_C * ll;
            SL += ll;
            AS += (float)(tbase + tl + 1) * g - bv;
        }
    }

#pragma unroll
    for (int o = 32; o > 0; o >>= 1) {
        SL += __shfl_xor(SL, o, 64);
        AS += __shfl_xor(AS, o, 64);
    }
    if (lane == 0) {
        ASp[q * S_SIMS + s] = AS;
        SLp[q * S_SIMS + s] = SL;
    }
}

// ---------------------------------------------------------------------------
// out = sum_s (sum_q AS[q][s]) * (sum_q SL[q][s]) / (T*S), f64 accumulate.
// ---------------------------------------------------------------------------
__global__ __launch_bounds__(1024) void mepg_reduce(
    const float* __restrict__ ASp, const float* __restrict__ SLp,
    float* __restrict__ out)
{
    __shared__ double sh[16];
    double acc = 0.0;
    for (int i = threadIdx.x; i < S_SIMS; i += 1024) {
        double a = 0.0, l = 0.0;
#pragma unroll
        for (int q = 0; q < NQ; ++q) {
            a += (double)ASp[q * S_SIMS + i];
            l += (double)SLp[q * S_SIMS + i];
        }
        acc += a * l;
    }
#pragma unroll
    for (int o = 32; o > 0; o >>= 1)
        acc += __shfl_xor(acc, o, 64);
    const int w = threadIdx.x >> 6, l = threadIdx.x & 63;
    if (l == 0) sh[w] = acc;
    __syncthreads();
    if (threadIdx.x < 16) {
        double a = sh[threadIdx.x];
#pragma unroll
        for (int o = 8; o > 0; o >>= 1)
            a += __shfl_xor(a, o, 16);
        if (threadIdx.x == 0)
            out[0] = (float)(a / ((double)T_LEN * (double)S_SIMS));
    }
}

extern "C" void kernel_launch(void* const* d_in, const int* in_sizes, int n_in,
                              void* d_out, int out_size, void* d_ws, size_t ws_size,
                              hipStream_t stream) {
    const float* state  = (const float*)d_in[0];
    const float* action = (const float*)d_in[1];
    const float* reward = (const float*)d_in[2];
    const float* pW1    = (const float*)d_in[3];
    const float* pb1    = (const float*)d_in[4];
    const float* pW2    = (const float*)d_in[5];
    const float* pb2    = (const float*)d_in[6];
    const float* bW1    = (const float*)d_in[7];
    const float* bb1    = (const float*)d_in[8];
    const float* bW2    = (const float*)d_in[9];
    const float* bb2    = (const float*)d_in[10];
    const float* sd     = (const float*)d_in[11];

    float* ASp = (float*)d_ws;                 // [NQ*S]
    float* SLp = ASp + NQ * S_SIMS;            // [NQ*S]
    float* wq  = SLp + NQ * S_SIMS;            // [H*WPK]

    mepg_pack<<<1, 64, 0, stream>>>(pW1, pb1, pW2, pb2, bW1, bb1, bW2, bb2, wq);

    dim3 block(256);
    dim3 grid(NQ * S_SIMS / 4);                // 16384 waves, 4 per block
    mepg_main<<<grid, block, 0, stream>>>(state, action, reward, wq,
                                          pb2, bb2, sd, ASp, SLp);
    mepg_reduce<<<1, 1024, 0, stream>>>(ASp, SLp, (float*)d_out);
}